// Round 1
// baseline (610.939 us; speedup 1.0000x reference)
//
#include <hip/hip_runtime.h>

// LoRA embedding: out[t,d] = weight[ids[t],d] + SCALING * sum_r B[d,r]*A[r,ids[t]]
// Shapes: ids[16384] (int32), weight[128000,1024] f32, A[8,128000] f32, B[1024,8] f32
// out[16384,1024] f32.

#define VOCAB_N 128000
#define EMB_D   1024
#define LORA_R  8
#define SCALING 2.0f

__global__ __launch_bounds__(256) void lora_embed_kernel(
    const int* __restrict__ ids,
    const float* __restrict__ weight,
    const float* __restrict__ A,    // [R, VOCAB]
    const float* __restrict__ Bm,   // [D, R] row-major
    float* __restrict__ out,
    int n_tokens, int tokens_per_block)
{
    // Each thread owns 4 contiguous dims: d0..d0+3. 256 threads * 4 = 1024 = EMB_D.
    const int d0 = threadIdx.x * 4;

    // Load this thread's lora_B fragment once: B[d0+j][r], j=0..3, r=0..7 (32 VGPRs).
    float b[4][LORA_R];
    #pragma unroll
    for (int j = 0; j < 4; ++j) {
        const float4* bp = reinterpret_cast<const float4*>(&Bm[(size_t)(d0 + j) * LORA_R]);
        float4 lo = bp[0];
        float4 hi = bp[1];
        b[j][0] = lo.x; b[j][1] = lo.y; b[j][2] = lo.z; b[j][3] = lo.w;
        b[j][4] = hi.x; b[j][5] = hi.y; b[j][6] = hi.z; b[j][7] = hi.w;
    }

    const int t0 = blockIdx.x * tokens_per_block;
    const int t1 = (t0 + tokens_per_block < n_tokens) ? (t0 + tokens_per_block) : n_tokens;

    for (int t = t0; t < t1; ++t) {
        const int v = ids[t];  // wave-uniform broadcast load

        // 8 lora_A scalars for this token (same address across lanes -> broadcast).
        float a[LORA_R];
        #pragma unroll
        for (int r = 0; r < LORA_R; ++r) {
            a[r] = A[(size_t)r * VOCAB_N + v];
        }

        // Gathered weight row, coalesced float4 across the block.
        const float4 w4 = *reinterpret_cast<const float4*>(
            &weight[(size_t)v * EMB_D + d0]);

        float acc0 = 0.f, acc1 = 0.f, acc2 = 0.f, acc3 = 0.f;
        #pragma unroll
        for (int r = 0; r < LORA_R; ++r) {
            acc0 = fmaf(b[0][r], a[r], acc0);
            acc1 = fmaf(b[1][r], a[r], acc1);
            acc2 = fmaf(b[2][r], a[r], acc2);
            acc3 = fmaf(b[3][r], a[r], acc3);
        }

        float4 o;
        o.x = w4.x + SCALING * acc0;
        o.y = w4.y + SCALING * acc1;
        o.z = w4.z + SCALING * acc2;
        o.w = w4.w + SCALING * acc3;
        *reinterpret_cast<float4*>(&out[(size_t)t * EMB_D + d0]) = o;
    }
}

extern "C" void kernel_launch(void* const* d_in, const int* in_sizes, int n_in,
                              void* d_out, int out_size, void* d_ws, size_t ws_size,
                              hipStream_t stream) {
    const int*   ids    = (const int*)d_in[0];
    const float* weight = (const float*)d_in[1];
    const float* A      = (const float*)d_in[2];
    const float* Bm     = (const float*)d_in[3];
    float*       out    = (float*)d_out;

    const int n_tokens = in_sizes[0];  // 4 * 4096 = 16384

    // ~2048 blocks -> 8 blocks/CU * 4 waves = full 32 waves/CU for latency hiding.
    int grid = n_tokens < 2048 ? n_tokens : 2048;
    int tokens_per_block = (n_tokens + grid - 1) / grid;

    lora_embed_kernel<<<grid, 256, 0, stream>>>(
        ids, weight, A, Bm, out, n_tokens, tokens_per_block);
}